// Round 2
// baseline (2049.360 us; speedup 1.0000x reference)
//
#include <hip/hip_runtime.h>

#define DIM 128

// ===========================================================================
// CSR-based path
// ===========================================================================

// ---- histogram: cnt[dst[e]]++ ---------------------------------------------
__global__ void hist_kernel(const int* __restrict__ dst, int* __restrict__ cnt, int E)
{
    const int e = blockIdx.x * 256 + threadIdx.x;
    if (e < E) atomicAdd(&cnt[dst[e]], 1);
}

// ---- single-block exclusive scan over cnt[N] -> pos[N] --------------------
__global__ __launch_bounds__(1024) void scan_kernel(const int* __restrict__ cnt,
                                                    int* __restrict__ pos, int N)
{
    __shared__ int sums[1024];
    const int t = threadIdx.x;
    const int C = (N + 1023) / 1024;
    const int lo = min(t * C, N);
    const int hi = min(lo + C, N);
    int s = 0;
    for (int i = lo; i < hi; ++i) s += cnt[i];
    sums[t] = s;
    __syncthreads();
    // Hillis-Steele inclusive scan in LDS
    for (int off = 1; off < 1024; off <<= 1) {
        int v = (t >= off) ? sums[t - off] : 0;
        __syncthreads();
        sums[t] += v;
        __syncthreads();
    }
    int run = (t == 0) ? 0 : sums[t - 1];
    for (int i = lo; i < hi; ++i) {
        pos[i] = run;
        run += cnt[i];
    }
}

// ---- CSR fill: slot = pos[dst]++ ; esrc[slot] = src -----------------------
// After this kernel pos[n] == end offset of node n (start = pos[n] - cnt[n]).
__global__ void fill_kernel(const int* __restrict__ src, const int* __restrict__ dst,
                            int* __restrict__ pos, int* __restrict__ esrc, int E)
{
    const int e = blockIdx.x * 256 + threadIdx.x;
    if (e < E) {
        const int slot = atomicAdd(&pos[dst[e]], 1);
        esrc[slot] = src[e];
    }
}

// ---- aggregate: one wave per node; lane holds dims [2l, 2l+1] -------------
__global__ __launch_bounds__(256) void aggregate_kernel(
    const float* __restrict__ h,
    const int* __restrict__ cnt,
    const int* __restrict__ pos,    // post-fill: pos[n] = end offset
    const int* __restrict__ esrc,
    float* __restrict__ mean,       // = d_out
    int N)
{
    const int wid = (blockIdx.x * 256 + threadIdx.x) >> 6;
    if (wid >= N) return;
    const int lane = threadIdx.x & 63;
    const int n = wid;
    const size_t col = (size_t)lane * 2;
    const int deg = cnt[n];
    if (deg == 0) {
        const float2 v = *(const float2*)&h[(size_t)n * DIM + col];
        *(float2*)&mean[(size_t)n * DIM + col] = v;
        return;
    }
    const int start = pos[n] - deg;
    float ax = 0.f, ay = 0.f;
#pragma unroll 2
    for (int k = 0; k < deg; ++k) {
        const int s = esrc[start + k];
        const float2 v = *(const float2*)&h[(size_t)s * DIM + col];
        ax += v.x; ay += v.y;
    }
    const float inv = 1.0f / (float)deg;
    *(float2*)&mean[(size_t)n * DIM + col] = make_float2(ax * inv, ay * inv);
}

// ---- tiny W transpose: W[j][d] -> Wt[d][j] --------------------------------
__global__ void transpose_kernel(const float* __restrict__ W, float* __restrict__ Wt)
{
    const int i = blockIdx.x * 256 + threadIdx.x;
    const int j = i >> 7;
    const int d = i & 127;
    Wt[d * DIM + j] = W[i];
}

// ---- update: out = ReLU(mean @ W^T + b), in place on d_out ----------------
// One wave handles 8 nodes; lane t computes output cols 2t, 2t+1.
__global__ __launch_bounds__(256) void update_kernel(
    const float* __restrict__ Wt, const float* __restrict__ bias,
    float* __restrict__ out, int N)
{
    const int t = threadIdx.x & 63;
    const int w = threadIdx.x >> 6;
    const int nbase = blockIdx.x * 32 + w * 8;

    const float* rowp[8];
#pragma unroll
    for (int n = 0; n < 8; ++n) {
        int node = nbase + n;
        rowp[n] = out + (size_t)(node < N ? node : 0) * DIM;
    }

    const float2 bb = *(const float2*)&bias[2 * t];
    float acc0[8], acc1[8];
#pragma unroll
    for (int n = 0; n < 8; ++n) { acc0[n] = bb.x; acc1[n] = bb.y; }

    for (int d4 = 0; d4 < DIM; d4 += 4) {
        float4 a[8];
#pragma unroll
        for (int n = 0; n < 8; ++n) a[n] = *(const float4*)&rowp[n][d4];
#pragma unroll
        for (int dd = 0; dd < 4; ++dd) {
            const float2 wt = *(const float2*)&Wt[(d4 + dd) * DIM + 2 * t];
#pragma unroll
            for (int n = 0; n < 8; ++n) {
                const float av = dd == 0 ? a[n].x : dd == 1 ? a[n].y : dd == 2 ? a[n].z : a[n].w;
                acc0[n] = fmaf(av, wt.x, acc0[n]);
                acc1[n] = fmaf(av, wt.y, acc1[n]);
            }
        }
    }

#pragma unroll
    for (int n = 0; n < 8; ++n) {
        int node = nbase + n;
        if (node < N) {
            *(float2*)&out[(size_t)node * DIM + 2 * t] =
                make_float2(fmaxf(acc0[n], 0.0f), fmaxf(acc1[n], 0.0f));
        }
    }
}

// ===========================================================================
// Fallback path (round-0 atomic version) — used only if ws_size is too small
// ===========================================================================
__global__ void scatter_kernel_fb(const float* __restrict__ h,
                                  const int* __restrict__ src,
                                  const int* __restrict__ dst,
                                  float* __restrict__ sum, float* __restrict__ cnt, int E)
{
    const int tid = threadIdx.x;
    const int e = blockIdx.x * 2 + (tid >> 7);
    const int d = tid & 127;
    if (e >= E) return;
    atomicAdd(&sum[(size_t)dst[e] * DIM + d], h[(size_t)src[e] * DIM + d]);
    if (d == 0) atomicAdd(&cnt[dst[e]], 1.0f);
}

__global__ __launch_bounds__(256) void update_kernel_fb(
    const float* __restrict__ h, const float* __restrict__ cnt,
    const float* __restrict__ Wt, const float* __restrict__ bias,
    float* __restrict__ out, int N)
{
    const int t = threadIdx.x & 63;
    const int w = threadIdx.x >> 6;
    const int nbase = blockIdx.x * 32 + w * 8;
    const float* rowp[8];
    float scale[8];
#pragma unroll
    for (int n = 0; n < 8; ++n) {
        int node = nbase + n;
        int cl = node < N ? node : N - 1;
        float c = cnt[cl];
        bool use_sum = (c > 0.0f);
        rowp[n] = (use_sum ? (const float*)out : h) + (size_t)cl * DIM;
        scale[n] = use_sum ? (1.0f / c) : 1.0f;
    }
    float acc0[8], acc1[8];
    const float b0 = bias[t], b1 = bias[t + 64];
#pragma unroll
    for (int n = 0; n < 8; ++n) { acc0[n] = b0; acc1[n] = b1; }
#pragma unroll 2
    for (int d = 0; d < DIM; ++d) {
        const float wt0 = Wt[d * DIM + t];
        const float wt1 = Wt[d * DIM + t + 64];
#pragma unroll
        for (int n = 0; n < 8; ++n) {
            const float a = rowp[n][d] * scale[n];
            acc0[n] = fmaf(a, wt0, acc0[n]);
            acc1[n] = fmaf(a, wt1, acc1[n]);
        }
    }
#pragma unroll
    for (int n = 0; n < 8; ++n) {
        int node = nbase + n;
        if (node < N) {
            out[(size_t)node * DIM + t]      = fmaxf(acc0[n], 0.0f);
            out[(size_t)node * DIM + t + 64] = fmaxf(acc1[n], 0.0f);
        }
    }
}

// ===========================================================================
extern "C" void kernel_launch(void* const* d_in, const int* in_sizes, int n_in,
                              void* d_out, int out_size, void* d_ws, size_t ws_size,
                              hipStream_t stream)
{
    const float* h  = (const float*)d_in[0];
    const int* src  = (const int*)d_in[1];
    const int* dst  = (const int*)d_in[2];
    const float* W  = (const float*)d_in[3];
    const float* b  = (const float*)d_in[4];
    float* out = (float*)d_out;

    const int N = in_sizes[0] / DIM;
    const int E = in_sizes[1];

    // CSR workspace layout
    const size_t off_cnt  = 0;
    const size_t off_pos  = (size_t)N * sizeof(int);
    const size_t off_esrc = off_pos + (size_t)N * sizeof(int);
    const size_t off_wt   = off_esrc + (size_t)E * sizeof(int);
    const size_t required = off_wt + (size_t)DIM * DIM * sizeof(float);

    if (ws_size >= required) {
        int*   cnt  = (int*)((char*)d_ws + off_cnt);
        int*   pos  = (int*)((char*)d_ws + off_pos);
        int*   esrc = (int*)((char*)d_ws + off_esrc);
        float* Wt   = (float*)((char*)d_ws + off_wt);

        hipMemsetAsync(cnt, 0, (size_t)N * sizeof(int), stream);
        transpose_kernel<<<(DIM * DIM) / 256, 256, 0, stream>>>(W, Wt);
        hist_kernel<<<(E + 255) / 256, 256, 0, stream>>>(dst, cnt, E);
        scan_kernel<<<1, 1024, 0, stream>>>(cnt, pos, N);
        fill_kernel<<<(E + 255) / 256, 256, 0, stream>>>(src, dst, pos, esrc, E);
        aggregate_kernel<<<(N * 64 + 255) / 256, 256, 0, stream>>>(h, cnt, pos, esrc, out, N);
        update_kernel<<<(N + 31) / 32, 256, 0, stream>>>(Wt, b, out, N);
    } else {
        // fallback: atomic scatter (round-0 path)
        float* cnt = (float*)d_ws;
        float* Wt  = (float*)((char*)d_ws + (1 << 19));
        hipMemsetAsync(out, 0, (size_t)N * DIM * sizeof(float), stream);
        hipMemsetAsync(cnt, 0, (size_t)N * sizeof(float), stream);
        transpose_kernel<<<(DIM * DIM) / 256, 256, 0, stream>>>(W, Wt);
        scatter_kernel_fb<<<(E + 1) / 2, 256, 0, stream>>>(h, src, dst, out, cnt, E);
        update_kernel_fb<<<(N + 31) / 32, 256, 0, stream>>>(h, cnt, Wt, b, out, N);
    }
}